// Round 12
// baseline (343.444 us; speedup 1.0000x reference)
//
#include <hip/hip_runtime.h>
#include <math.h>

#define HH 512
#define WW 512
#define NB 64
#define HW (HH*WW)

struct GaussK { float k[13]; };

__device__ __forceinline__ float idenv(int i) {
    return (float)(2*i - (WW-1)) / (float)(WW-1);
}

#define DEF_OFF ((float)((2.0 + 4.0/511.0)/2.0))
#define BOUND   ((float)(2.0/512.0*8.0))

typedef float vf2 __attribute__((ext_vector_type(2), aligned(4)));

// horizontal 13-tap conv of one row held as a[8] per lane (cols 8l..8l+7),
// halo via neighbor-lane shuffles, reflect at row ends.
__device__ __forceinline__ void hconv_row(const float (&a)[8], int lane, const GaussK& gk, float (&o)[8]) {
    float win[20];                       // cols 8l-6 .. 8l+13
    #pragma unroll
    for (int i = 0; i < 6; ++i) {
        float v = __shfl_up(a[i+2], 1, 64);
        win[i] = (lane == 0) ? a[6-i] : v;
    }
    #pragma unroll
    for (int i = 6; i < 14; ++i) win[i] = a[i-6];
    #pragma unroll
    for (int i = 14; i < 20; ++i) {
        float v = __shfl_down(a[i-14], 1, 64);
        win[i] = (lane == 63) ? a[20-i] : v;
    }
    #pragma unroll
    for (int j = 0; j < 8; ++j) {
        float acc = 0.f;
        #pragma unroll
        for (int i = 0; i < 13; ++i) acc = fmaf(gk.k[i], win[j+i], acc);
        o[j] = acc;
    }
}

// x-channel pipeline for one row: hconv (incl col-1) + relu-diff scan + clips.
__device__ __forceinline__ void xscan_row(const float (&a)[8], int lane, const GaussK& gk, float* row0) {
    float win[21];                       // cols 8l-7 .. 8l+13
    #pragma unroll
    for (int i = 0; i < 7; ++i) {
        float v = __shfl_up(a[i+1], 1, 64);
        win[i] = (lane == 0) ? a[7-i] : v;
    }
    #pragma unroll
    for (int i = 0; i < 8; ++i) win[7+i] = a[i];
    #pragma unroll
    for (int i = 15; i < 21; ++i) {
        float v = __shfl_down(a[i-15], 1, 64);
        win[i] = (lane == 63) ? a[21-i] : v;
    }
    float s[9];
    #pragma unroll
    for (int j = 0; j < 9; ++j) {
        float acc = 0.f;
        #pragma unroll
        for (int i = 0; i < 13; ++i) acc = fmaf(gk.k[i], win[j+i], acc);
        s[j] = acc + idenv(8*lane - 1 + j) + DEF_OFF;
    }
    if (lane == 0) s[0] = 0.f;

    float qs[8], q = 0.f;
    #pragma unroll
    for (int j = 1; j < 9; ++j) { q += fmaxf(s[j] - s[j-1], 0.f); qs[j-1] = q; }
    float inc = q;
    #pragma unroll
    for (int d = 1; d < 64; d <<= 1) {
        float t = __shfl_up(inc, d, 64);
        if (lane >= d) inc += t;
    }
    float excl = inc - q;

    float4 g0, g1;
    float* gp0 = (float*)&g0;
    float* gp1 = (float*)&g1;
    #pragma unroll
    for (int j = 0; j < 8; ++j) {
        int wcol = lane*8 + j;
        float sx = excl + qs[j];
        float p = sx - DEF_OFF - idenv(wcol);
        p = fminf(fmaxf(p, -BOUND), BOUND);
        float g = p + idenv(wcol);
        g = fminf(fmaxf(g, -1.f), 1.f);
        if (j < 4) gp0[j] = g; else gp1[j-4] = g;
    }
    *(float4*)(row0 + lane*8)     = g0;
    *(float4*)(row0 + lane*8 + 4) = g1;
}

// ---- fused prep: vblur(ch0)+hblur+row-scan -> plane0  AND  hblur(ch1) -> plane1 ----
// 4 rows per wave: 16-row vconv window shared across 4 outputs.
__global__ void __launch_bounds__(256) k_prep(const float* __restrict__ prim, float* __restrict__ out, GaussK gk) {
    int lane = threadIdx.x & 63;
    int bid  = (int)blockIdx.x;                  // 2048 blocks
    int work = (bid & 7)*256 + (bid >> 3);       // XCD-chunked, bijective
    int gw   = work*4 + ((int)threadIdx.x >> 6); // 0..8191
    int b    = gw >> 7;                          // 128 groups per batch
    int h0   = (gw & 127)*4;

    const float4* src0 = (const float4*)(prim + (size_t)b*2*HW);       // ch0
    const float*  src1 = prim + ((size_t)b*2 + 1)*HW;                  // ch1
    float* plane0 = out + (size_t)b*3*HW;
    float* plane1 = out + ((size_t)b*3 + 1)*HW;

    // ---- ch0 vertical conv for rows h0..h0+3, streaming 16-row window ----
    float a[4][8];
    #pragma unroll
    for (int r = 0; r < 4; ++r)
        #pragma unroll
        for (int j = 0; j < 8; ++j) a[r][j] = 0.f;

    #pragma unroll
    for (int i = 0; i < 16; ++i) {
        int rr = h0 - 6 + i;
        rr = rr < 0 ? -rr : (rr > HH-1 ? 2*(HH-1) - rr : rr);
        float4 u0 = src0[(size_t)rr*128 + 2*lane];
        float4 u1 = src0[(size_t)rr*128 + 2*lane + 1];
        float vv[8] = {u0.x,u0.y,u0.z,u0.w,u1.x,u1.y,u1.z,u1.w};
        #pragma unroll
        for (int r = 0; r < 4; ++r) {
            if (i >= r && i <= r + 12) {
                #pragma unroll
                for (int j = 0; j < 8; ++j) a[r][j] = fmaf(gk.k[i-r], vv[j], a[r][j]);
            }
        }
    }

    // ---- hblur of ch1 rows h0..h0+3 -> plane1 ----
    #pragma unroll
    for (int r = 0; r < 4; ++r) {
        const float4* c4 = (const float4*)(src1 + (size_t)(h0+r)*WW);
        float4 u0 = c4[2*lane];
        float4 u1 = c4[2*lane + 1];
        float c[8] = {u0.x,u0.y,u0.z,u0.w,u1.x,u1.y,u1.z,u1.w};
        float o[8];
        hconv_row(c, lane, gk, o);
        float* row1 = plane1 + (size_t)(h0+r)*WW;
        *(float4*)(row1 + lane*8)     = make_float4(o[0],o[1],o[2],o[3]);
        *(float4*)(row1 + lane*8 + 4) = make_float4(o[4],o[5],o[6],o[7]);
    }

    // ---- x-channel scan rows h0..h0+3 -> plane0 ----
    #pragma unroll
    for (int r = 0; r < 4; ++r)
        xscan_row(a[r], lane, gk, plane0 + (size_t)(h0+r)*WW);
}

// ---- fused y-scan + bilinear sample: plane1 -> grid-y (regs) -> final output ----
// launch_bounds(1024,2): VGPR ceiling 256 so the 32 grid-x loads + gather
// pipeline stay in registers. grid-x loads issued BEFORE the conv/scan VALU
// phase so their latency hides under compute.
__global__ void __launch_bounds__(1024, 2) k_yssamp(const float* __restrict__ image, float* __restrict__ out, GaussK gk) {
    __shared__ float segsum[16][64];
    int bid  = (int)blockIdx.x;          // 512 blocks
    int work = (bid & 7)*64 + (bid >> 3);// XCD j owns batches j*8..j*8+7
    int b    = work >> 3;
    int wt   = work & 7;
    int lane = threadIdx.x & 63;
    int ws   = threadIdx.x >> 6;         // 0..15
    int w    = wt*64 + lane;
    const float* p1 = out + ((size_t)b*3 + 1)*HW + w;
    int r0 = ws*32;

    float v[45];                          // plane1 rows r0-7 .. r0+37, reflected
    #pragma unroll
    for (int j = 0; j < 45; ++j) {
        int r = r0 - 7 + j;
        r = r < 0 ? -r : (r > HH-1 ? 2*(HH-1) - r : r);
        v[j] = p1[(size_t)r*WW];
    }

    const float* ib = image + (size_t)b*3*HW;
    float*       ob = out   + (size_t)b*3*HW;

    // issue all 32 grid-x loads now; latency hides under the conv/scan below
    float gxv[32];
    #pragma unroll
    for (int n = 0; n < 32; ++n)
        gxv[n] = ob[(size_t)(r0 + n)*WW + w];

    float sprev;
    if (ws == 0) {
        sprev = 0.f;
    } else {
        float acc = 0.f;
        #pragma unroll
        for (int i = 0; i < 13; ++i) acc = fmaf(gk.k[i], v[i], acc);
        sprev = acc + idenv(r0 - 1) + DEF_OFF;
    }

    float q[32];
    float run = 0.f;
    #pragma unroll
    for (int n = 0; n < 32; ++n) {
        float acc = 0.f;
        #pragma unroll
        for (int i = 0; i < 13; ++i) acc = fmaf(gk.k[i], v[n+1+i], acc);
        float s = acc + idenv(r0 + n) + DEF_OFF;
        run += fmaxf(s - sprev, 0.f);
        q[n] = run;
        sprev = s;
    }
    segsum[ws][lane] = run;
    __syncthreads();
    float off = 0.f;
    for (int k = 0; k < ws; ++k) off += segsum[k][lane];

    #pragma unroll
    for (int n = 0; n < 32; ++n) {
        int h = r0 + n;
        size_t poff = (size_t)h*WW + w;
        float p = off + q[n] - DEF_OFF - idenv(h);
        p = fminf(fmaxf(p, -BOUND), BOUND);
        float gy = p + idenv(h);
        gy = fminf(fmaxf(gy, -1.f), 1.f);
        float gx = gxv[n];

        float fx = (gx + 1.f) * 0.5f * (float)(WW-1);
        float fy = (gy + 1.f) * 0.5f * (float)(HH-1);
        float x0f = floorf(fx), y0f = floorf(fy);
        float wx = fx - x0f, wy = fy - y0f;
        int x0 = (int)x0f, y0 = (int)y0f;
        int y1 = y0 + 1; if (y1 > HH-1) y1 = HH-1;
        bool shx = x0 > WW-2;               // x0==511 => wx==0 exactly
        int xb = shx ? WW-2 : x0;
        size_t g0 = (size_t)y0*WW + xb;
        size_t g1 = (size_t)y1*WW + xb;
        float w11 = wx*wy;
        float w01 = wx - w11;
        float w10 = wy - w11;
        float w00 = 1.f - wx - wy + w11;
        #pragma unroll
        for (int c = 0; c < 3; ++c) {
            const float* ip = ib + (size_t)c*HW;
            vf2 t  = *(const vf2*)(ip + g0);
            vf2 bo = *(const vf2*)(ip + g1);
            float a00 = shx ? t.y  : t.x;
            float a10 = shx ? bo.y : bo.x;
            float r = a00*w00 + t.y*w01 + a10*w10 + bo.y*w11;
            __builtin_nontemporal_store(r, ob + (size_t)c*HW + poff);
        }
    }
}

extern "C" void kernel_launch(void* const* d_in, const int* in_sizes, int n_in,
                              void* d_out, int out_size, void* d_ws, size_t ws_size,
                              hipStream_t stream) {
    const float* image = (const float*)d_in[0];
    const float* prim  = (const float*)d_in[1];
    float* out = (float*)d_out;

    GaussK gk;
    {
        double sigma = 13.0*0.15 + 0.35;   // 2.3
        double pdf[13], sum = 0.0;
        for (int i = 0; i < 13; ++i) {
            double t = (double)(i - 6);
            pdf[i] = exp(-0.5*(t/sigma)*(t/sigma));
            sum += pdf[i];
        }
        for (int i = 0; i < 13; ++i) gk.k[i] = (float)(pdf[i]/sum);
    }

    k_prep  <<<2048, 256,  0, stream>>>(prim, out, gk);
    k_yssamp<<<NB*8, 1024, 0, stream>>>(image, out, gk);
}

// Round 13
// 224.924 us; speedup vs baseline: 1.5269x; 1.5269x over previous
//
#include <hip/hip_runtime.h>
#include <math.h>

#define HH 512
#define WW 512
#define NB 64
#define HW (HH*WW)

struct GaussK { float k[13]; };

__device__ __forceinline__ float idenv(int i) {
    return (float)(2*i - (WW-1)) / (float)(WW-1);
}

#define DEF_OFF ((float)((2.0 + 4.0/511.0)/2.0))
#define BOUND   ((float)(2.0/512.0*8.0))

typedef float vf2 __attribute__((ext_vector_type(2), aligned(4)));

// horizontal 13-tap conv of one row held as a[8] per lane (cols 8l..8l+7),
// halo via neighbor-lane shuffles, reflect at row ends.
__device__ __forceinline__ void hconv_row(const float (&a)[8], int lane, const GaussK& gk, float (&o)[8]) {
    float win[20];                       // cols 8l-6 .. 8l+13
    #pragma unroll
    for (int i = 0; i < 6; ++i) {
        float v = __shfl_up(a[i+2], 1, 64);
        win[i] = (lane == 0) ? a[6-i] : v;
    }
    #pragma unroll
    for (int i = 6; i < 14; ++i) win[i] = a[i-6];
    #pragma unroll
    for (int i = 14; i < 20; ++i) {
        float v = __shfl_down(a[i-14], 1, 64);
        win[i] = (lane == 63) ? a[20-i] : v;
    }
    #pragma unroll
    for (int j = 0; j < 8; ++j) {
        float acc = 0.f;
        #pragma unroll
        for (int i = 0; i < 13; ++i) acc = fmaf(gk.k[i], win[j+i], acc);
        o[j] = acc;
    }
}

// x-channel pipeline for one row: hconv (incl col-1) + relu-diff scan + clips.
__device__ __forceinline__ void xscan_row(const float (&a)[8], int lane, const GaussK& gk, float* row0) {
    float win[21];                       // cols 8l-7 .. 8l+13
    #pragma unroll
    for (int i = 0; i < 7; ++i) {
        float v = __shfl_up(a[i+1], 1, 64);
        win[i] = (lane == 0) ? a[7-i] : v;
    }
    #pragma unroll
    for (int i = 0; i < 8; ++i) win[7+i] = a[i];
    #pragma unroll
    for (int i = 15; i < 21; ++i) {
        float v = __shfl_down(a[i-15], 1, 64);
        win[i] = (lane == 63) ? a[21-i] : v;
    }
    float s[9];
    #pragma unroll
    for (int j = 0; j < 9; ++j) {
        float acc = 0.f;
        #pragma unroll
        for (int i = 0; i < 13; ++i) acc = fmaf(gk.k[i], win[j+i], acc);
        s[j] = acc + idenv(8*lane - 1 + j) + DEF_OFF;
    }
    if (lane == 0) s[0] = 0.f;

    float qs[8], q = 0.f;
    #pragma unroll
    for (int j = 1; j < 9; ++j) { q += fmaxf(s[j] - s[j-1], 0.f); qs[j-1] = q; }
    float inc = q;
    #pragma unroll
    for (int d = 1; d < 64; d <<= 1) {
        float t = __shfl_up(inc, d, 64);
        if (lane >= d) inc += t;
    }
    float excl = inc - q;

    float4 g0, g1;
    float* gp0 = (float*)&g0;
    float* gp1 = (float*)&g1;
    #pragma unroll
    for (int j = 0; j < 8; ++j) {
        int wcol = lane*8 + j;
        float sx = excl + qs[j];
        float p = sx - DEF_OFF - idenv(wcol);
        p = fminf(fmaxf(p, -BOUND), BOUND);
        float g = p + idenv(wcol);
        g = fminf(fmaxf(g, -1.f), 1.f);
        if (j < 4) gp0[j] = g; else gp1[j-4] = g;
    }
    *(float4*)(row0 + lane*8)     = g0;
    *(float4*)(row0 + lane*8 + 4) = g1;
}

// ---- fused prep: vblur(ch0)+hblur+row-scan -> plane0  AND  hblur(ch1) -> plane1 ----
// 4 rows per wave: 16-row vconv window shared across 4 outputs.
__global__ void __launch_bounds__(256) k_prep(const float* __restrict__ prim, float* __restrict__ out, GaussK gk) {
    int lane = threadIdx.x & 63;
    int bid  = (int)blockIdx.x;                  // 2048 blocks
    int work = (bid & 7)*256 + (bid >> 3);       // XCD-chunked, bijective
    int gw   = work*4 + ((int)threadIdx.x >> 6); // 0..8191
    int b    = gw >> 7;                          // 128 groups per batch
    int h0   = (gw & 127)*4;

    const float4* src0 = (const float4*)(prim + (size_t)b*2*HW);       // ch0
    const float*  src1 = prim + ((size_t)b*2 + 1)*HW;                  // ch1
    float* plane0 = out + (size_t)b*3*HW;
    float* plane1 = out + ((size_t)b*3 + 1)*HW;

    float a[4][8];
    #pragma unroll
    for (int r = 0; r < 4; ++r)
        #pragma unroll
        for (int j = 0; j < 8; ++j) a[r][j] = 0.f;

    #pragma unroll
    for (int i = 0; i < 16; ++i) {
        int rr = h0 - 6 + i;
        rr = rr < 0 ? -rr : (rr > HH-1 ? 2*(HH-1) - rr : rr);
        float4 u0 = src0[(size_t)rr*128 + 2*lane];
        float4 u1 = src0[(size_t)rr*128 + 2*lane + 1];
        float vv[8] = {u0.x,u0.y,u0.z,u0.w,u1.x,u1.y,u1.z,u1.w};
        #pragma unroll
        for (int r = 0; r < 4; ++r) {
            if (i >= r && i <= r + 12) {
                #pragma unroll
                for (int j = 0; j < 8; ++j) a[r][j] = fmaf(gk.k[i-r], vv[j], a[r][j]);
            }
        }
    }

    #pragma unroll
    for (int r = 0; r < 4; ++r) {
        const float4* c4 = (const float4*)(src1 + (size_t)(h0+r)*WW);
        float4 u0 = c4[2*lane];
        float4 u1 = c4[2*lane + 1];
        float c[8] = {u0.x,u0.y,u0.z,u0.w,u1.x,u1.y,u1.z,u1.w};
        float o[8];
        hconv_row(c, lane, gk, o);
        float* row1 = plane1 + (size_t)(h0+r)*WW;
        *(float4*)(row1 + lane*8)     = make_float4(o[0],o[1],o[2],o[3]);
        *(float4*)(row1 + lane*8 + 4) = make_float4(o[4],o[5],o[6],o[7]);
    }

    #pragma unroll
    for (int r = 0; r < 4; ++r)
        xscan_row(a[r], lane, gk, plane0 + (size_t)(h0+r)*WW);
}

// ---- fused y-scan + bilinear sample: plane1 -> grid-y (regs) -> final output ----
// launch_bounds(1024, 1): 1 block/CU (16 waves) -> VGPR ceiling 128, so the
// post-barrier 32-load grid-x batch and the gather pipeline stay in registers.
// XCD-chunked: each XCD owns 8 consecutive batches -> image gathers L2-resident.
__global__ void __launch_bounds__(1024, 1) k_yssamp(const float* __restrict__ image, float* __restrict__ out, GaussK gk) {
    __shared__ float segsum[16][64];
    int bid  = (int)blockIdx.x;          // 512 blocks
    int work = (bid & 7)*64 + (bid >> 3);// XCD j owns batches j*8..j*8+7
    int b    = work >> 3;
    int wt   = work & 7;
    int lane = threadIdx.x & 63;
    int ws   = threadIdx.x >> 6;         // 0..15
    int w    = wt*64 + lane;
    const float* p1 = out + ((size_t)b*3 + 1)*HW + w;
    int r0 = ws*32;

    float v[45];                          // plane1 rows r0-7 .. r0+37, reflected
    #pragma unroll
    for (int j = 0; j < 45; ++j) {
        int r = r0 - 7 + j;
        r = r < 0 ? -r : (r > HH-1 ? 2*(HH-1) - r : r);
        v[j] = p1[(size_t)r*WW];
    }

    float sprev;
    if (ws == 0) {
        sprev = 0.f;
    } else {
        float acc = 0.f;
        #pragma unroll
        for (int i = 0; i < 13; ++i) acc = fmaf(gk.k[i], v[i], acc);
        sprev = acc + idenv(r0 - 1) + DEF_OFF;
    }

    float q[32];
    float run = 0.f;
    #pragma unroll
    for (int n = 0; n < 32; ++n) {
        float acc = 0.f;
        #pragma unroll
        for (int i = 0; i < 13; ++i) acc = fmaf(gk.k[i], v[n+1+i], acc);
        float s = acc + idenv(r0 + n) + DEF_OFF;
        run += fmaxf(s - sprev, 0.f);
        q[n] = run;
        sprev = s;
    }
    segsum[ws][lane] = run;
    __syncthreads();
    float off = 0.f;
    for (int k = 0; k < ws; ++k) off += segsum[k][lane];

    const float* ib = image + (size_t)b*3*HW;
    float*       ob = out   + (size_t)b*3*HW;

    // batch-load all 32 grid-x values (coalesced; v[] is dead -> VGPRs available)
    float gxv[32];
    #pragma unroll
    for (int n = 0; n < 32; ++n)
        gxv[n] = ob[(size_t)(r0 + n)*WW + w];

    #pragma unroll
    for (int n = 0; n < 32; ++n) {
        int h = r0 + n;
        size_t poff = (size_t)h*WW + w;
        float p = off + q[n] - DEF_OFF - idenv(h);
        p = fminf(fmaxf(p, -BOUND), BOUND);
        float gy = p + idenv(h);
        gy = fminf(fmaxf(gy, -1.f), 1.f);
        float gx = gxv[n];

        float fx = (gx + 1.f) * 0.5f * (float)(WW-1);
        float fy = (gy + 1.f) * 0.5f * (float)(HH-1);
        float x0f = floorf(fx), y0f = floorf(fy);
        float wx = fx - x0f, wy = fy - y0f;
        int x0 = (int)x0f, y0 = (int)y0f;
        int y1 = y0 + 1; if (y1 > HH-1) y1 = HH-1;
        bool shx = x0 > WW-2;               // x0==511 => wx==0 exactly
        int xb = shx ? WW-2 : x0;
        size_t g0 = (size_t)y0*WW + xb;
        size_t g1 = (size_t)y1*WW + xb;
        float w11 = wx*wy;
        float w01 = wx - w11;
        float w10 = wy - w11;
        float w00 = 1.f - wx - wy + w11;
        #pragma unroll
        for (int c = 0; c < 3; ++c) {
            const float* ip = ib + (size_t)c*HW;
            vf2 t  = *(const vf2*)(ip + g0);
            vf2 bo = *(const vf2*)(ip + g1);
            float a00 = shx ? t.y  : t.x;
            float a10 = shx ? bo.y : bo.x;
            float r = a00*w00 + t.y*w01 + a10*w10 + bo.y*w11;
            __builtin_nontemporal_store(r, ob + (size_t)c*HW + poff);
        }
    }
}

extern "C" void kernel_launch(void* const* d_in, const int* in_sizes, int n_in,
                              void* d_out, int out_size, void* d_ws, size_t ws_size,
                              hipStream_t stream) {
    const float* image = (const float*)d_in[0];
    const float* prim  = (const float*)d_in[1];
    float* out = (float*)d_out;

    GaussK gk;
    {
        double sigma = 13.0*0.15 + 0.35;   // 2.3
        double pdf[13], sum = 0.0;
        for (int i = 0; i < 13; ++i) {
            double t = (double)(i - 6);
            pdf[i] = exp(-0.5*(t/sigma)*(t/sigma));
            sum += pdf[i];
        }
        for (int i = 0; i < 13; ++i) gk.k[i] = (float)(pdf[i]/sum);
    }

    k_prep  <<<2048, 256,  0, stream>>>(prim, out, gk);
    k_yssamp<<<NB*8, 1024, 0, stream>>>(image, out, gk);
}